// Round 4
// baseline (312.073 us; speedup 1.0000x reference)
//
#include <hip/hip_runtime.h>
#include <hip/hip_bf16.h>

typedef unsigned short u16;
typedef __bf16 bf16_t;
typedef bf16_t bf16x8 __attribute__((ext_vector_type(8)));
typedef float f32x4 __attribute__((ext_vector_type(4)));
typedef u16 u16x8 __attribute__((ext_vector_type(8)));

#define MFMA16(A,B,C) __builtin_amdgcn_mfma_f32_16x16x32_bf16(A,B,C,0,0,0)

#define CB 512
#define TT 1024
#define NH 8
#define DH 64
static __constant__ float kScale = 0.044194173824159216f; // 1/sqrt(512)

static __device__ __forceinline__ u16 f2b(float f) {
  unsigned u = __float_as_uint(f);
  unsigned r = u + 0x7FFFu + ((u >> 16) & 1u);
  return (u16)(r >> 16);
}
static __device__ __forceinline__ float b2f(u16 u) {
  return __uint_as_float(((unsigned)u) << 16);
}
static __device__ __forceinline__ bf16x8 ldb8(const u16* p) {
  return *reinterpret_cast<const bf16x8*>(p);
}

// ---------- fp32 -> bf16 elementwise (8/thread) ----------
__global__ __launch_bounds__(256)
void convert_bf16(const float* __restrict__ src, u16* __restrict__ dst, int n8)
{
  int i = blockIdx.x * 256 + threadIdx.x;
  if (i >= n8) return;
  const float4 a = ((const float4*)src)[i * 2 + 0];
  const float4 b = ((const float4*)src)[i * 2 + 1];
  u16x8 o;
  o[0] = f2b(a.x); o[1] = f2b(a.y); o[2] = f2b(a.z); o[3] = f2b(a.w);
  o[4] = f2b(b.x); o[5] = f2b(b.y); o[6] = f2b(b.z); o[7] = f2b(b.w);
  *(u16x8*)(dst + (size_t)i * 8) = o;
}

// ---------- Wo [512][512] fp32 -> [Wo|Wo] [512][1024] bf16 ----------
__global__ __launch_bounds__(256)
void convert_wo2(const float* __restrict__ src, u16* __restrict__ dst)
{
  int i = blockIdx.x * 256 + threadIdx.x;     // 65536 groups of 8
  int m = i >> 7;
  int k0 = (i & 127) * 8;
  const float* s = src + (size_t)m * 512 + (k0 & 511);
  const float4 a = *(const float4*)s;
  const float4 b = *(const float4*)(s + 4);
  u16x8 o;
  o[0] = f2b(a.x); o[1] = f2b(a.y); o[2] = f2b(a.z); o[3] = f2b(a.w);
  o[4] = f2b(b.x); o[5] = f2b(b.y); o[6] = f2b(b.z); o[7] = f2b(b.w);
  *(u16x8*)(dst + (size_t)m * 1024 + k0) = o;
}

// ---------- pos_emb [512][2047] fp32 -> posT [2048][512] bf16 (row 2047 = 0) ----------
__global__ __launch_bounds__(256)
void transpose_pe(const float* __restrict__ pe, u16* __restrict__ posT)
{
  __shared__ float tile[64][65];
  int j0 = blockIdx.x * 64, c0 = blockIdx.y * 64;
  for (int e = threadIdx.x; e < 4096; e += 256) {
    int cc = e >> 6, jj = e & 63;
    int j = j0 + jj;
    tile[jj][cc] = (j < 2047) ? pe[(size_t)(c0 + cc) * 2047 + j] : 0.f;
  }
  __syncthreads();
  for (int e = threadIdx.x; e < 4096; e += 256) {
    int jj = e >> 6, cc = e & 63;
    posT[(size_t)(j0 + jj) * 512 + c0 + cc] = f2b(tile[jj][cc]);
  }
}

// ---------- LayerNorm over channel axis; emits xnT [b][t][c] bf16 ----------
__global__ __launch_bounds__(256)
void ln_kernel(const float* __restrict__ x, const float* __restrict__ gamma,
               const float* __restrict__ beta, u16* __restrict__ xnT)
{
  __shared__ float sred[8][33], ssred[8][33];
  int tl = threadIdx.x & 31, cg = threadIdx.x >> 5;
  int t = blockIdx.x * 32 + tl;
  int b = blockIdx.y;
  const float* xb = x + (size_t)b * CB * TT + t;
  float s = 0.f, ss = 0.f;
  for (int c = cg * 64; c < cg * 64 + 64; ++c) {
    float v = xb[(size_t)c * TT];
    s += v; ss += v * v;
  }
  sred[cg][tl] = s; ssred[cg][tl] = ss;
  __syncthreads();
  float S = 0.f, SS = 0.f;
  #pragma unroll
  for (int g = 0; g < 8; ++g) { S += sred[g][tl]; SS += ssred[g][tl]; }
  float mean = S * (1.f / 512.f);
  float var = SS * (1.f / 512.f) - mean * mean;
  float rstd = rsqrtf(var + 1e-5f);
  u16* orow = xnT + ((size_t)b * TT + t) * CB;
  for (int c8 = 0; c8 < 8; ++c8) {
    int c = cg * 64 + c8 * 8;
    u16x8 o;
    #pragma unroll
    for (int j = 0; j < 8; ++j) {
      float v = xb[(size_t)(c + j) * TT];
      o[j] = f2b((v - mean) * rstd * gamma[c + j] + beta[c + j]);
    }
    *(u16x8*)(orow + c) = o;
  }
}

// ---------- MFMA GEMM: out[m,n] = sum_k W[m,k]*XT[n,k] + bias(m) ----------
template<int K, int OMODE, int DUAL>
__global__ __launch_bounds__(256)
void gemm_mfma(const u16* __restrict__ W, const u16* __restrict__ XT,
               long xStride, long oStride, int Nout,
               const float* __restrict__ b0, const float* __restrict__ bA,
               const float* __restrict__ bB,
               void* __restrict__ out1v, void* __restrict__ out2v)
{
  const int tid = threadIdx.x, w = tid >> 6, lane = tid & 63;
  const int ln16 = lane & 15, kg = lane >> 4;
  const int n0 = blockIdx.x * 64 + (w >> 1) * 32;
  const int m0 = blockIdx.y * 32 + (w & 1) * 16;
  const int z = blockIdx.z;
  const u16* Arow = W + (size_t)(m0 + ln16) * K + kg * 8;
  const u16* B0row = XT + (size_t)z * xStride + (size_t)(n0 + ln16) * K + kg * 8;
  const u16* B1row = B0row + (size_t)16 * K;
  f32x4 acc0 = {0.f, 0.f, 0.f, 0.f}, acc1 = {0.f, 0.f, 0.f, 0.f};
  #pragma unroll 4
  for (int ks = 0; ks < K / 32; ++ks) {
    bf16x8 a = ldb8(Arow + ks * 32);
    bf16x8 bb0 = ldb8(B0row + ks * 32);
    bf16x8 bb1 = ldb8(B1row + ks * 32);
    acc0 = MFMA16(a, bb0, acc0);
    acc1 = MFMA16(a, bb1, acc1);
  }
  float add1[4], add2[4];
  #pragma unroll
  for (int jr = 0; jr < 4; ++jr) {
    int m = m0 + kg * 4 + jr;
    float base = b0 ? b0[m] : 0.f;
    add1[jr] = base + (bA ? bA[m] : 0.f);
    add2[jr] = base + (bB ? bB[m] : 0.f);
  }
  #pragma unroll
  for (int nt = 0; nt < 2; ++nt) {
    const f32x4 acc = nt ? acc1 : acc0;
    const int n = n0 + nt * 16 + ln16;
    if constexpr (OMODE == 0) {
      float* out1 = (float*)out1v;
      #pragma unroll
      for (int jr = 0; jr < 4; ++jr)
        out1[(size_t)z * oStride + (size_t)(m0 + kg * 4 + jr) * Nout + n] = acc[jr] + add1[jr];
    } else if constexpr (OMODE == 2) {
      u16* out1 = (u16*)out1v;
      #pragma unroll
      for (int jr = 0; jr < 4; ++jr)
        out1[(size_t)z * oStride + (size_t)(m0 + kg * 4 + jr) * Nout + n] = f2b(acc[jr] + add1[jr]);
    } else {
      const size_t o = (size_t)z * oStride +
                       ((size_t)(m0 >> 6) * Nout + n) * 64 + (m0 & 63) + kg * 4;
      ushort4 s1;
      s1.x = f2b(acc[0] + add1[0]); s1.y = f2b(acc[1] + add1[1]);
      s1.z = f2b(acc[2] + add1[2]); s1.w = f2b(acc[3] + add1[3]);
      *reinterpret_cast<ushort4*>((u16*)out1v + o) = s1;
      if constexpr (DUAL) {
        ushort4 s2;
        s2.x = f2b(acc[0] + add2[0]); s2.y = f2b(acc[1] + add2[1]);
        s2.z = f2b(acc[2] + add2[2]); s2.w = f2b(acc[3] + add2[3]);
        *reinterpret_cast<ushort4*>((u16*)out2v + o) = s2;
      }
    }
  }
}

// ---------- Pass 1 (MFMA): partial l over a ki half ----------
// grid 2048: bh=(bid&7)+8*((bid>>3)&3); rest=bid>>5; qi0=(rest&31)*32; part=rest>>5.
// Each wave handles 2 ki-chunks of 64 (chunk = part*8 + c*4 + w).
__global__ __launch_bounds__(256)
void stats_mfma(const u16* __restrict__ qu, const u16* __restrict__ qv,
                const u16* __restrict__ kk_, const u16* __restrict__ pp,
                const float* __restrict__ xmask, float* __restrict__ ls)
{
  const int tid = threadIdx.x;
  const int w = tid >> 6, lane = tid & 63;
  const int ln16 = lane & 15, kg = lane >> 4;
  const int bid = blockIdx.x;
  const int bh = (bid & 7) + 8 * ((bid >> 3) & 3);
  const int rest = bid >> 5;
  const int qi0 = (rest & 31) * 32;
  const int part = rest >> 5;
  const int b = bh >> 3, h = bh & 7;
  const u16* quP = qu + (size_t)bh * TT * DH;
  const u16* qvP = qv + (size_t)bh * TT * DH;
  const u16* kP  = kk_ + (size_t)bh * TT * DH;
  const u16* pP  = pp + (size_t)h * 2048 * DH;

  __shared__ u16 G[4][32][100];   // per-wave pos band, bf16
  __shared__ float red[4][32];

  bf16x8 qa[2][2], va[2][2];
  #pragma unroll
  for (int mt = 0; mt < 2; ++mt)
    #pragma unroll
    for (int kc = 0; kc < 2; ++kc) {
      const size_t o = (size_t)(qi0 + mt * 16 + ln16) * DH + kc * 32 + kg * 8;
      qa[mt][kc] = ldb8(&quP[o]);
      va[mt][kc] = ldb8(&qvP[o]);
    }
  float aq[2][4];
  #pragma unroll
  for (int mt = 0; mt < 2; ++mt)
    #pragma unroll
    for (int jr = 0; jr < 4; ++jr)
      aq[mt][jr] = (xmask[b * TT + qi0 + mt * 16 + kg * 4 + jr] - 1.f) * 10000.f;

  float rs[2][4] = {};
  for (int c = 0; c < 2; ++c) {
    const int ki0 = (part * 8 + c * 4 + w) * 64;
    const int j0 = ki0 - qi0 + 992;
    #pragma unroll
    for (int nt = 0; nt < 6; ++nt) {
      const size_t po = (size_t)(j0 + nt * 16 + ln16) * DH + kg * 8;
      bf16x8 pb0 = ldb8(&pP[po]);
      bf16x8 pb1 = ldb8(&pP[po + 32]);
      #pragma unroll
      for (int mt = 0; mt < 2; ++mt) {
        f32x4 g = {0.f, 0.f, 0.f, 0.f};
        g = MFMA16(va[mt][0], pb0, g);
        g = MFMA16(va[mt][1], pb1, g);
        #pragma unroll
        for (int jr = 0; jr < 4; ++jr)
          G[w][mt * 16 + kg * 4 + jr][nt * 16 + ln16] = f2b(g[jr]);
      }
    }
    #pragma unroll
    for (int nt = 0; nt < 4; ++nt) {
      const size_t ko = (size_t)(ki0 + nt * 16 + ln16) * DH + kg * 8;
      bf16x8 kb0 = ldb8(&kP[ko]);
      bf16x8 kb1 = ldb8(&kP[ko + 32]);
      const float ak = (xmask[b * TT + ki0 + nt * 16 + ln16] - 1.f) * 10000.f;
      #pragma unroll
      for (int mt = 0; mt < 2; ++mt) {
        f32x4 dd = {0.f, 0.f, 0.f, 0.f};
        dd = MFMA16(qa[mt][0], kb0, dd);
        dd = MFMA16(qa[mt][1], kb1, dd);
        #pragma unroll
        for (int jr = 0; jr < 4; ++jr) {
          const int qrow = mt * 16 + kg * 4 + jr;
          const int u = nt * 16 + ln16 - qrow + 31;
          const float s = (dd[jr] + b2f(G[w][qrow][u])) * kScale + aq[mt][jr] + ak;
          rs[mt][jr] += __expf(s);
        }
      }
    }
  }
  #pragma unroll
  for (int mt = 0; mt < 2; ++mt)
    #pragma unroll
    for (int jr = 0; jr < 4; ++jr) {
      float v = rs[mt][jr];
      v += __shfl_xor(v, 1); v += __shfl_xor(v, 2);
      v += __shfl_xor(v, 4); v += __shfl_xor(v, 8);
      rs[mt][jr] = v;
    }
  if (ln16 == 0) {
    #pragma unroll
    for (int mt = 0; mt < 2; ++mt)
      #pragma unroll
      for (int jr = 0; jr < 4; ++jr)
        red[w][mt * 16 + kg * 4 + jr] = rs[mt][jr];
  }
  __syncthreads();
  if (tid < 32)
    ls[(size_t)part * 32768 + (size_t)bh * TT + qi0 + tid] =
        red[0][tid] + red[1][tid] + red[2][tid] + red[3][tid];
}

// ---------- Pass 2 (MFMA): partial ctx; t-tile 32, qi split in 2 ----------
// grid 2048: bh=(bid&7)+8*((bid>>3)&3); rest=bid>>5; t0=(rest&31)*32; part=rest>>5.
// ctx2[b][t][part*512 + h*64 + d]
__global__ __launch_bounds__(256)
void ctx_mfma(const u16* __restrict__ qu, const u16* __restrict__ qv,
              const u16* __restrict__ kk_, const u16* __restrict__ vv,
              const u16* __restrict__ pp, const float* __restrict__ xmask,
              const float* __restrict__ ls, u16* __restrict__ ctx2)
{
  const int tid = threadIdx.x;
  const int w = tid >> 6, lane = tid & 63;
  const int ln16 = lane & 15, kg = lane >> 4;
  const int bid = blockIdx.x;
  const int bh = (bid & 7) + 8 * ((bid >> 3) & 3);
  const int rest = bid >> 5;
  const int t0 = (rest & 31) * 32;
  const int part = rest >> 5;
  const int b = bh >> 3, h = bh & 7;
  const u16* quP = qu + (size_t)bh * TT * DH;
  const u16* qvP = qv + (size_t)bh * TT * DH;
  const u16* kP  = kk_ + (size_t)bh * TT * DH;
  const u16* vP  = vv + (size_t)bh * DH * TT;    // [d][t]
  const u16* pP  = pp + (size_t)h * 2048 * DH;
  const float* lsP = ls + (size_t)bh * TT;

  __shared__ float G[4][16][51];                 // per-wave pos band [qi 16][u 48]
  __shared__ __align__(16) u16 P[32][72];        // P[t][qi_local], bf16

  bf16x8 ka[2][2];
  #pragma unroll
  for (int nt = 0; nt < 2; ++nt)
    #pragma unroll
    for (int kc = 0; kc < 2; ++kc)
      ka[nt][kc] = ldb8(&kP[(size_t)(t0 + nt * 16 + ln16) * DH + kc * 32 + kg * 8]);
  float at2[2];
  #pragma unroll
  for (int nt = 0; nt < 2; ++nt)
    at2[nt] = (xmask[b * TT + t0 + nt * 16 + ln16] - 1.f) * 10000.f;

  f32x4 cacc[2] = {};
  for (int qc = part * 8; qc < part * 8 + 8; ++qc) {
    const int qw = qc * 64 + w * 16;
    const int j0 = t0 - qw + 1008;
    const size_t qo = (size_t)(qw + ln16) * DH + kg * 8;
    bf16x8 qa0 = ldb8(&quP[qo]), qa1 = ldb8(&quP[qo + 32]);
    bf16x8 va0 = ldb8(&qvP[qo]), va1 = ldb8(&qvP[qo + 32]);
    #pragma unroll
    for (int nt = 0; nt < 3; ++nt) {
      const size_t po = (size_t)(j0 + nt * 16 + ln16) * DH + kg * 8;
      bf16x8 pb0 = ldb8(&pP[po]), pb1 = ldb8(&pP[po + 32]);
      f32x4 g = {0.f, 0.f, 0.f, 0.f};
      g = MFMA16(va0, pb0, g);
      g = MFMA16(va1, pb1, g);
      #pragma unroll
      for (int jr = 0; jr < 4; ++jr)
        G[w][kg * 4 + jr][nt * 16 + ln16] = g[jr];
    }
    float linv[4], aqv[4];
    #pragma unroll
    for (int jr = 0; jr < 4; ++jr) {
      const int qi = qw + kg * 4 + jr;
      linv[jr] = 1.f / (lsP[qi] + lsP[32768 + qi]);
      aqv[jr] = (xmask[b * TT + qi] - 1.f) * 10000.f;
    }
    __syncthreads();
    #pragma unroll
    for (int nt = 0; nt < 2; ++nt) {
      f32x4 dd = {0.f, 0.f, 0.f, 0.f};
      dd = MFMA16(qa0, ka[nt][0], dd);
      dd = MFMA16(qa1, ka[nt][1], dd);
      unsigned lo = 0, hi = 0;
      #pragma unroll
      for (int jr = 0; jr < 4; ++jr) {
        const int qrow = kg * 4 + jr;
        const int u = nt * 16 + ln16 - qrow + 15;
        const float s = (dd[jr] + G[w][qrow][u]) * kScale + aqv[jr] + at2[nt];
        const float e = __expf(s) * linv[jr];
        const unsigned bb = f2b(e);
        if (jr == 0) lo = bb; else if (jr == 1) lo |= bb << 16;
        else if (jr == 2) hi = bb; else hi |= bb << 16;
      }
      *reinterpret_cast<uint2*>(&P[nt * 16 + ln16][w * 16 + kg * 4]) = make_uint2(lo, hi);
    }
    __syncthreads();
    const size_t vbase = (size_t)(w * 16 + ln16) * TT + qc * 64 + kg * 8;
    bf16x8 vf0 = ldb8(&vP[vbase]), vf1 = ldb8(&vP[vbase + 32]);
    #pragma unroll
    for (int nt = 0; nt < 2; ++nt) {
      bf16x8 pb0 = *reinterpret_cast<const bf16x8*>(&P[nt * 16 + ln16][kg * 8]);
      bf16x8 pb1 = *reinterpret_cast<const bf16x8*>(&P[nt * 16 + ln16][32 + kg * 8]);
      cacc[nt] = MFMA16(vf0, pb0, cacc[nt]);
      cacc[nt] = MFMA16(vf1, pb1, cacc[nt]);
    }
  }
  #pragma unroll
  for (int nt = 0; nt < 2; ++nt) {
    const int t = t0 + nt * 16 + ln16;
    ushort4 s4;
    s4.x = f2b(cacc[nt][0]); s4.y = f2b(cacc[nt][1]);
    s4.z = f2b(cacc[nt][2]); s4.w = f2b(cacc[nt][3]);
    *reinterpret_cast<ushort4*>(
      &ctx2[((size_t)b * TT + t) * 1024 + part * 512 + h * 64 + w * 16 + kg * 4]) = s4;
  }
}

// ---------- launch ----------
extern "C" void kernel_launch(void* const* d_in, const int* in_sizes, int n_in,
                              void* d_out, int out_size, void* d_ws, size_t ws_size,
                              hipStream_t stream)
{
  (void)in_sizes; (void)n_in; (void)out_size;
  const float* x     = (const float*)d_in[0];
  const float* pe    = (const float*)d_in[1];
  const float* xm    = (const float*)d_in[2];
  const float* gamma = (const float*)d_in[3];
  const float* beta  = (const float*)d_in[4];
  const float* Wq    = (const float*)d_in[5];
  const float* bq    = (const float*)d_in[6];
  const float* Wk    = (const float*)d_in[7];
  const float* bk    = (const float*)d_in[8];
  const float* Wv    = (const float*)d_in[9];
  const float* bv    = (const float*)d_in[10];
  const float* Wp    = (const float*)d_in[11];
  const float* ub    = (const float*)d_in[12];
  const float* vb    = (const float*)d_in[13];
  const float* Wo    = (const float*)d_in[14];
  const float* bo    = (const float*)d_in[15];

  // workspace layout (bytes); ctx2 overlays {xnT, posT, Wq/k/v/p-bf16} (all dead)
  char* ws = (char*)d_ws;
  u16* xnT  = (u16*)(ws + 0);          // [4][1024][512] bf16   (4 MiB)
  u16* posT = (u16*)(ws + 4194304);    // [2048][512] bf16      (2 MiB)
  u16* Wqb  = (u16*)(ws + 6291456);    // [512][512] bf16
  u16* Wkb  = (u16*)(ws + 6815744);
  u16* Wvb  = (u16*)(ws + 7340032);
  u16* Wpb  = (u16*)(ws + 7864320);
  u16* ctx2 = (u16*)(ws + 0);          // [4][1024][1024] bf16  (8 MiB, overlay)
  u16* quB  = (u16*)(ws + 8388608);    // [32][1024][64] bf16
  u16* qvB  = (u16*)(ws + 12582912);
  u16* kB   = (u16*)(ws + 16777216);
  u16* vB   = (u16*)(ws + 20971520);   // [32][64][1024] bf16
  u16* pB   = (u16*)(ws + 25165824);   // [8][2048][64] bf16
  float* lsB = (float*)(ws + 27262976);// [2][32][1024] f32 partials
  u16* Wo2  = (u16*)(ws + 27525120);   // [512][1024] bf16
  if (ws_size < 28573696) return;

  dim3 blk(256);
  const long XS = (long)TT * CB;       // xnT per-batch stride (elems)
  const long QS = (long)NH * TT * DH;  // q/k/v per-batch stride (elems)

  convert_bf16<<<dim3(128), blk, 0, stream>>>(Wq, Wqb, 32768);
  convert_bf16<<<dim3(128), blk, 0, stream>>>(Wk, Wkb, 32768);
  convert_bf16<<<dim3(128), blk, 0, stream>>>(Wv, Wvb, 32768);
  convert_bf16<<<dim3(128), blk, 0, stream>>>(Wp, Wpb, 32768);
  convert_wo2<<<dim3(256), blk, 0, stream>>>(Wo, Wo2);
  transpose_pe<<<dim3(32, 8), blk, 0, stream>>>(pe, posT);
  ln_kernel<<<dim3(32, 4), blk, 0, stream>>>(x, gamma, beta, xnT);

  gemm_mfma<512, 1, 1><<<dim3(16, 16, 4), blk, 0, stream>>>(
      Wqb, xnT, XS, QS, TT, bq, ub, vb, quB, qvB);
  gemm_mfma<512, 1, 0><<<dim3(16, 16, 4), blk, 0, stream>>>(
      Wkb, xnT, XS, QS, TT, bk, nullptr, nullptr, kB, nullptr);
  gemm_mfma<512, 2, 0><<<dim3(16, 16, 4), blk, 0, stream>>>(
      Wvb, xnT, XS, QS, TT, bv, nullptr, nullptr, vB, nullptr);
  gemm_mfma<512, 1, 0><<<dim3(32, 16, 1), blk, 0, stream>>>(
      Wpb, posT, 0, 0, 2048, nullptr, nullptr, nullptr, pB, nullptr);

  stats_mfma<<<dim3(2048), blk, 0, stream>>>(quB, qvB, kB, pB, xm, lsB);
  ctx_mfma<<<dim3(2048), blk, 0, stream>>>(quB, qvB, kB, vB, pB, xm, lsB, ctx2);

  gemm_mfma<1024, 0, 0><<<dim3(16, 16, 4), blk, 0, stream>>>(
      Wo2, ctx2, (long)TT * 1024, (long)CB * TT, TT, bo, nullptr, nullptr,
      (float*)d_out, nullptr);
}

// Round 5
// 311.295 us; speedup vs baseline: 1.0025x; 1.0025x over previous
//
#include <hip/hip_runtime.h>
#include <hip/hip_bf16.h>

typedef unsigned short u16;
typedef __bf16 bf16_t;
typedef bf16_t bf16x8 __attribute__((ext_vector_type(8)));
typedef float f32x4 __attribute__((ext_vector_type(4)));
typedef u16 u16x8 __attribute__((ext_vector_type(8)));

#define MFMA16(A,B,C) __builtin_amdgcn_mfma_f32_16x16x32_bf16(A,B,C,0,0,0)

#define CB 512
#define TT 1024
#define NH 8
#define DH 64
static __constant__ float kScale = 0.044194173824159216f; // 1/sqrt(512)

static __device__ __forceinline__ u16 f2b(float f) {
  unsigned u = __float_as_uint(f);
  unsigned r = u + 0x7FFFu + ((u >> 16) & 1u);
  return (u16)(r >> 16);
}
static __device__ __forceinline__ float b2f(u16 u) {
  return __uint_as_float(((unsigned)u) << 16);
}
static __device__ __forceinline__ bf16x8 ldb8(const u16* p) {
  return *reinterpret_cast<const bf16x8*>(p);
}

// ---------- Wq/Wk/Wv/Wp fp32 -> stacked bf16 [2048][512] ----------
__global__ __launch_bounds__(256)
void convert_qkvp(const float* __restrict__ Wq, const float* __restrict__ Wk,
                  const float* __restrict__ Wv, const float* __restrict__ Wp,
                  u16* __restrict__ Wstk)
{
  int i = blockIdx.x * 256 + threadIdx.x;      // 131072 groups of 8
  int sel = i >> 15, loc = i & 32767;
  const float* src = (sel == 0) ? Wq : (sel == 1) ? Wk : (sel == 2) ? Wv : Wp;
  const float4 a = ((const float4*)src)[loc * 2 + 0];
  const float4 b = ((const float4*)src)[loc * 2 + 1];
  u16x8 o;
  o[0] = f2b(a.x); o[1] = f2b(a.y); o[2] = f2b(a.z); o[3] = f2b(a.w);
  o[4] = f2b(b.x); o[5] = f2b(b.y); o[6] = f2b(b.z); o[7] = f2b(b.w);
  *(u16x8*)(Wstk + (size_t)i * 8) = o;
}

// ---------- Wo [512][512] fp32 -> [Wo|Wo|Wo|Wo] [512][2048] bf16 ----------
__global__ __launch_bounds__(256)
void convert_wo4(const float* __restrict__ src, u16* __restrict__ dst)
{
  int i = blockIdx.x * 256 + threadIdx.x;      // 32768 groups of 8
  int m = i >> 6;
  int k0 = (i & 63) * 8;
  const float* s = src + (size_t)m * 512 + k0;
  const float4 a = *(const float4*)s;
  const float4 b = *(const float4*)(s + 4);
  u16x8 o;
  o[0] = f2b(a.x); o[1] = f2b(a.y); o[2] = f2b(a.z); o[3] = f2b(a.w);
  o[4] = f2b(b.x); o[5] = f2b(b.y); o[6] = f2b(b.z); o[7] = f2b(b.w);
  #pragma unroll
  for (int q = 0; q < 4; ++q)
    *(u16x8*)(dst + (size_t)m * 2048 + q * 512 + k0) = o;
}

// ---------- pos_emb [512][2047] fp32 -> posT [2048][512] bf16 (row 2047 = 0) ----------
__global__ __launch_bounds__(256)
void transpose_pe(const float* __restrict__ pe, u16* __restrict__ posT)
{
  __shared__ float tile[64][65];
  int j0 = blockIdx.x * 64, c0 = blockIdx.y * 64;
  for (int e = threadIdx.x; e < 4096; e += 256) {
    int cc = e >> 6, jj = e & 63;
    int j = j0 + jj;
    tile[jj][cc] = (j < 2047) ? pe[(size_t)(c0 + cc) * 2047 + j] : 0.f;
  }
  __syncthreads();
  for (int e = threadIdx.x; e < 4096; e += 256) {
    int jj = e >> 6, cc = e & 63;
    posT[(size_t)(j0 + jj) * 512 + c0 + cc] = f2b(tile[jj][cc]);
  }
}

// ---------- LayerNorm over channel axis; emits xnT [b][t][c] bf16 ----------
__global__ __launch_bounds__(256)
void ln_kernel(const float* __restrict__ x, const float* __restrict__ gamma,
               const float* __restrict__ beta, u16* __restrict__ xnT)
{
  __shared__ float sred[8][33], ssred[8][33];
  int tl = threadIdx.x & 31, cg = threadIdx.x >> 5;
  int t = blockIdx.x * 32 + tl;
  int b = blockIdx.y;
  const float* xb = x + (size_t)b * CB * TT + t;
  float s = 0.f, ss = 0.f;
  for (int c = cg * 64; c < cg * 64 + 64; ++c) {
    float v = xb[(size_t)c * TT];
    s += v; ss += v * v;
  }
  sred[cg][tl] = s; ssred[cg][tl] = ss;
  __syncthreads();
  float S = 0.f, SS = 0.f;
  #pragma unroll
  for (int g = 0; g < 8; ++g) { S += sred[g][tl]; SS += ssred[g][tl]; }
  float mean = S * (1.f / 512.f);
  float var = SS * (1.f / 512.f) - mean * mean;
  float rstd = rsqrtf(var + 1e-5f);
  u16* orow = xnT + ((size_t)b * TT + t) * CB;
  for (int c8 = 0; c8 < 8; ++c8) {
    int c = cg * 64 + c8 * 8;
    u16x8 o;
    #pragma unroll
    for (int j = 0; j < 8; ++j) {
      float v = xb[(size_t)(c + j) * TT];
      o[j] = f2b((v - mean) * rstd * gamma[c + j] + beta[c + j]);
    }
    *(u16x8*)(orow + c) = o;
  }
}

// ---------- fused q/k/v projection (MFMA), K=512 ----------
// Wstk rows: [0,512)=Wq, [512,1024)=Wk, [1024,1536)=Wv.
// qu -> [bh][t][d] (+bq+ub), k -> [bh][t][d] (+bk), v -> [bh][d][t] (+bv).
__global__ __launch_bounds__(256)
void proj_qkv(const u16* __restrict__ Wstk, const u16* __restrict__ xnT,
              const float* __restrict__ bq, const float* __restrict__ ub,
              const float* __restrict__ bk, const float* __restrict__ bv,
              u16* __restrict__ quB, u16* __restrict__ kB, u16* __restrict__ vB)
{
  const int tid = threadIdx.x, w = tid >> 6, lane = tid & 63;
  const int ln16 = lane & 15, kg = lane >> 4;
  const int n0 = blockIdx.x * 64 + (w >> 1) * 32;
  const int my = blockIdx.y;                 // 0..47
  const int sec = my >> 4;                   // 0=q 1=k 2=v
  const int m0l = (my & 15) * 32 + (w & 1) * 16;
  const int z = blockIdx.z;
  const long XS = (long)TT * CB;
  const long QS = (long)NH * TT * DH;
  const u16* Arow = Wstk + (size_t)(sec * 512 + m0l + ln16) * 512 + kg * 8;
  const u16* B0row = xnT + (size_t)z * XS + (size_t)(n0 + ln16) * 512 + kg * 8;
  const u16* B1row = B0row + (size_t)16 * 512;
  f32x4 acc0 = {0.f, 0.f, 0.f, 0.f}, acc1 = {0.f, 0.f, 0.f, 0.f};
  #pragma unroll 4
  for (int ks = 0; ks < 16; ++ks) {
    bf16x8 a = ldb8(Arow + ks * 32);
    bf16x8 bb0 = ldb8(B0row + ks * 32);
    bf16x8 bb1 = ldb8(B1row + ks * 32);
    acc0 = MFMA16(a, bb0, acc0);
    acc1 = MFMA16(a, bb1, acc1);
  }
  float add[4];
  #pragma unroll
  for (int jr = 0; jr < 4; ++jr) {
    int m = m0l + kg * 4 + jr;
    add[jr] = (sec == 0) ? (bq[m] + ub[m]) : (sec == 1) ? bk[m] : bv[m];
  }
  if (sec < 2) {
    u16* dst = sec ? kB : quB;
    #pragma unroll
    for (int nt = 0; nt < 2; ++nt) {
      const f32x4 acc = nt ? acc1 : acc0;
      const int n = n0 + nt * 16 + ln16;
      const size_t o = (size_t)z * QS +
                       ((size_t)(m0l >> 6) * TT + n) * 64 + (m0l & 63) + kg * 4;
      ushort4 s4;
      s4.x = f2b(acc[0] + add[0]); s4.y = f2b(acc[1] + add[1]);
      s4.z = f2b(acc[2] + add[2]); s4.w = f2b(acc[3] + add[3]);
      *reinterpret_cast<ushort4*>(dst + o) = s4;
    }
  } else {
    #pragma unroll
    for (int nt = 0; nt < 2; ++nt) {
      const f32x4 acc = nt ? acc1 : acc0;
      const int n = n0 + nt * 16 + ln16;
      #pragma unroll
      for (int jr = 0; jr < 4; ++jr)
        vB[(size_t)z * QS + (size_t)(m0l + kg * 4 + jr) * TT + n] = f2b(acc[jr] + add[jr]);
    }
  }
}

// ---------- generic MFMA GEMM (p projection + output projection) ----------
template<int K, int OMODE>
__global__ __launch_bounds__(256)
void gemm_mfma(const u16* __restrict__ W, const u16* __restrict__ XT,
               long xStride, long oStride, int Nout,
               const float* __restrict__ b0, void* __restrict__ outv)
{
  const int tid = threadIdx.x, w = tid >> 6, lane = tid & 63;
  const int ln16 = lane & 15, kg = lane >> 4;
  const int n0 = blockIdx.x * 64 + (w >> 1) * 32;
  const int m0 = blockIdx.y * 32 + (w & 1) * 16;
  const int z = blockIdx.z;
  const u16* Arow = W + (size_t)(m0 + ln16) * K + kg * 8;
  const u16* B0row = XT + (size_t)z * xStride + (size_t)(n0 + ln16) * K + kg * 8;
  const u16* B1row = B0row + (size_t)16 * K;
  f32x4 acc0 = {0.f, 0.f, 0.f, 0.f}, acc1 = {0.f, 0.f, 0.f, 0.f};
  #pragma unroll 4
  for (int ks = 0; ks < K / 32; ++ks) {
    bf16x8 a = ldb8(Arow + ks * 32);
    bf16x8 bb0 = ldb8(B0row + ks * 32);
    bf16x8 bb1 = ldb8(B1row + ks * 32);
    acc0 = MFMA16(a, bb0, acc0);
    acc1 = MFMA16(a, bb1, acc1);
  }
  float add[4];
  #pragma unroll
  for (int jr = 0; jr < 4; ++jr)
    add[jr] = b0 ? b0[m0 + kg * 4 + jr] : 0.f;
  #pragma unroll
  for (int nt = 0; nt < 2; ++nt) {
    const f32x4 acc = nt ? acc1 : acc0;
    const int n = n0 + nt * 16 + ln16;
    if constexpr (OMODE == 0) {
      float* out = (float*)outv;
      #pragma unroll
      for (int jr = 0; jr < 4; ++jr)
        out[(size_t)z * oStride + (size_t)(m0 + kg * 4 + jr) * Nout + n] = acc[jr] + add[jr];
    } else {
      const size_t o = (size_t)z * oStride +
                       ((size_t)(m0 >> 6) * Nout + n) * 64 + (m0 & 63) + kg * 4;
      ushort4 s4;
      s4.x = f2b(acc[0] + add[0]); s4.y = f2b(acc[1] + add[1]);
      s4.z = f2b(acc[2] + add[2]); s4.w = f2b(acc[3] + add[3]);
      *reinterpret_cast<ushort4*>((u16*)outv + o) = s4;
    }
  }
}

// ---------- corr[h][j] = sum_d (vb-ub)[h][d] * p[h][j][d] ----------
__global__ __launch_bounds__(256)
void corr_kernel(const u16* __restrict__ pp, const float* __restrict__ ub,
                 const float* __restrict__ vb, float* __restrict__ corr)
{
  const int h = blockIdx.y;
  const int j = blockIdx.x * 256 + threadIdx.x;
  __shared__ float dl[64];
  if (threadIdx.x < 64)
    dl[threadIdx.x] = vb[h * 64 + threadIdx.x] - ub[h * 64 + threadIdx.x];
  __syncthreads();
  const u16* prow = pp + ((size_t)h * 2048 + j) * 64;
  float s = 0.f;
  #pragma unroll
  for (int d8 = 0; d8 < 8; ++d8) {
    union { bf16x8 v; u16 u[8]; } pu;
    pu.v = ldb8(prow + d8 * 8);
    #pragma unroll
    for (int e = 0; e < 8; ++e) s += b2f(pu.u[e]) * dl[d8 * 8 + e];
  }
  corr[h * 2048 + j] = s;
}

// ---------- Pass 1 (MFMA): partial l over a ki half ----------
// grid 2048: bh=(bid&7)+8*((bid>>3)&3); rest=bid>>5; qi0=(rest&31)*32; part=rest>>5.
__global__ __launch_bounds__(256)
void stats_mfma(const u16* __restrict__ qu, const u16* __restrict__ kk_,
                const u16* __restrict__ pp, const float* __restrict__ corr,
                const float* __restrict__ xmask, float* __restrict__ ls)
{
  const int tid = threadIdx.x;
  const int w = tid >> 6, lane = tid & 63;
  const int ln16 = lane & 15, kg = lane >> 4;
  const int bid = blockIdx.x;
  const int bh = (bid & 7) + 8 * ((bid >> 3) & 3);
  const int rest = bid >> 5;
  const int qi0 = (rest & 31) * 32;
  const int part = rest >> 5;
  const int b = bh >> 3, h = bh & 7;
  const u16* quP = qu + (size_t)bh * TT * DH;
  const u16* kP  = kk_ + (size_t)bh * TT * DH;
  const u16* pP  = pp + (size_t)h * 2048 * DH;
  const float* corrP = corr + (h << 11);

  __shared__ u16 G[4][32][100];   // per-wave pos band (incl corr), bf16
  __shared__ float red[4][32];

  bf16x8 qa[2][2];
  #pragma unroll
  for (int mt = 0; mt < 2; ++mt)
    #pragma unroll
    for (int kc = 0; kc < 2; ++kc)
      qa[mt][kc] = ldb8(&quP[(size_t)(qi0 + mt * 16 + ln16) * DH + kc * 32 + kg * 8]);
  float aq[2][4];
  #pragma unroll
  for (int mt = 0; mt < 2; ++mt)
    #pragma unroll
    for (int jr = 0; jr < 4; ++jr)
      aq[mt][jr] = (xmask[b * TT + qi0 + mt * 16 + kg * 4 + jr] - 1.f) * 10000.f;

  float rs[2][4] = {};
  for (int c = 0; c < 2; ++c) {
    const int ki0 = (part * 8 + c * 4 + w) * 64;
    const int j0 = ki0 - qi0 + 992;
    #pragma unroll
    for (int nt = 0; nt < 6; ++nt) {
      const size_t po = (size_t)(j0 + nt * 16 + ln16) * DH + kg * 8;
      bf16x8 pb0 = ldb8(&pP[po]);
      bf16x8 pb1 = ldb8(&pP[po + 32]);
      const float cval = corrP[j0 + nt * 16 + ln16];
      #pragma unroll
      for (int mt = 0; mt < 2; ++mt) {
        f32x4 g = {0.f, 0.f, 0.f, 0.f};
        g = MFMA16(qa[mt][0], pb0, g);
        g = MFMA16(qa[mt][1], pb1, g);
        #pragma unroll
        for (int jr = 0; jr < 4; ++jr)
          G[w][mt * 16 + kg * 4 + jr][nt * 16 + ln16] = f2b(g[jr] + cval);
      }
    }
    #pragma unroll
    for (int nt = 0; nt < 4; ++nt) {
      const size_t ko = (size_t)(ki0 + nt * 16 + ln16) * DH + kg * 8;
      bf16x8 kb0 = ldb8(&kP[ko]);
      bf16x8 kb1 = ldb8(&kP[ko + 32]);
      const float ak = (xmask[b * TT + ki0 + nt * 16 + ln16] - 1.f) * 10000.f;
      #pragma unroll
      for (int mt = 0; mt < 2; ++mt) {
        f32x4 dd = {0.f, 0.f, 0.f, 0.f};
        dd = MFMA16(qa[mt][0], kb0, dd);
        dd = MFMA16(qa[mt][1], kb1, dd);
        #pragma unroll
        for (int jr = 0; jr < 4; ++jr) {
          const int qrow = mt * 16 + kg * 4 + jr;
          const int u = nt * 16 + ln16 - qrow + 31;
          const float s = (dd[jr] + b2f(G[w][qrow][u])) * kScale + aq[mt][jr] + ak;
          rs[mt][jr] += __expf(s);
        }
      }
    }
  }
  #pragma unroll
  for (int mt = 0; mt < 2; ++mt)
    #pragma unroll
    for (int jr = 0; jr < 4; ++jr) {
      float v = rs[mt][jr];
      v += __shfl_xor(v, 1); v += __shfl_xor(v, 2);
      v += __shfl_xor(v, 4); v += __shfl_xor(v, 8);
      rs[mt][jr] = v;
    }
  if (ln16 == 0) {
    #pragma unroll
    for (int mt = 0; mt < 2; ++mt)
      #pragma unroll
      for (int jr = 0; jr < 4; ++jr)
        red[w][mt * 16 + kg * 4 + jr] = rs[mt][jr];
  }
  __syncthreads();
  if (tid < 32)
    ls[(size_t)part * 32768 + (size_t)bh * TT + qi0 + tid] =
        red[0][tid] + red[1][tid] + red[2][tid] + red[3][tid];
}

// ---------- Pass 2 (MFMA): partial ctx; t-tile 64, qi split 4-way ----------
// grid 2048: bh=(bid&7)+8*((bid>>3)&3); rest=bid>>5; t0=(rest&15)*64; part=rest>>4.
// ctx2[b][t][part*512 + h*64 + d]
__global__ __launch_bounds__(256)
void ctx_mfma(const u16* __restrict__ qu, const u16* __restrict__ kk_,
              const u16* __restrict__ vv, const u16* __restrict__ pp,
              const float* __restrict__ corr, const float* __restrict__ xmask,
              const float* __restrict__ ls, u16* __restrict__ ctx2)
{
  const int tid = threadIdx.x;
  const int w = tid >> 6, lane = tid & 63;
  const int ln16 = lane & 15, kg = lane >> 4;
  const int bid = blockIdx.x;
  const int bh = (bid & 7) + 8 * ((bid >> 3) & 3);
  const int rest = bid >> 5;
  const int t0 = (rest & 15) * 64;
  const int part = rest >> 4;
  const int b = bh >> 3, h = bh & 7;
  const u16* quP = qu + (size_t)bh * TT * DH;
  const u16* kP  = kk_ + (size_t)bh * TT * DH;
  const u16* vP  = vv + (size_t)bh * DH * TT;    // [d][t]
  const u16* pP  = pp + (size_t)h * 2048 * DH;
  const float* corrP = corr + (h << 11);
  const float* lsP = ls + (size_t)bh * TT;

  __shared__ u16 G[4][16][84];                   // per-wave pos band (incl corr)
  __shared__ __align__(16) u16 P[64][80];        // P[t][qi_local], bf16

  bf16x8 ka[4][2];
  #pragma unroll
  for (int nt = 0; nt < 4; ++nt)
    #pragma unroll
    for (int kc = 0; kc < 2; ++kc)
      ka[nt][kc] = ldb8(&kP[(size_t)(t0 + nt * 16 + ln16) * DH + kc * 32 + kg * 8]);
  float at4[4];
  #pragma unroll
  for (int nt = 0; nt < 4; ++nt)
    at4[nt] = (xmask[b * TT + t0 + nt * 16 + ln16] - 1.f) * 10000.f;

  f32x4 cacc[4] = {};
  for (int qc = part * 4; qc < part * 4 + 4; ++qc) {
    const int qw = qc * 64 + w * 16;
    const int j0 = t0 - qw + 1008;
    const size_t qo = (size_t)(qw + ln16) * DH + kg * 8;
    bf16x8 qa0 = ldb8(&quP[qo]), qa1 = ldb8(&quP[qo + 32]);
    #pragma unroll
    for (int nt = 0; nt < 5; ++nt) {
      const size_t po = (size_t)(j0 + nt * 16 + ln16) * DH + kg * 8;
      bf16x8 pb0 = ldb8(&pP[po]), pb1 = ldb8(&pP[po + 32]);
      const float cval = corrP[j0 + nt * 16 + ln16];
      f32x4 g = {0.f, 0.f, 0.f, 0.f};
      g = MFMA16(qa0, pb0, g);
      g = MFMA16(qa1, pb1, g);
      #pragma unroll
      for (int jr = 0; jr < 4; ++jr)
        G[w][kg * 4 + jr][nt * 16 + ln16] = f2b(g[jr] + cval);
    }
    float linv[4], aqv[4];
    #pragma unroll
    for (int jr = 0; jr < 4; ++jr) {
      const int qi = qw + kg * 4 + jr;
      linv[jr] = 1.f / (lsP[qi] + lsP[32768 + qi]);
      aqv[jr] = (xmask[b * TT + qi] - 1.f) * 10000.f;
    }
    __syncthreads();                             // prev chunk's PV reads done
    #pragma unroll
    for (int nt = 0; nt < 4; ++nt) {
      f32x4 dd = {0.f, 0.f, 0.f, 0.f};
      dd = MFMA16(qa0, ka[nt][0], dd);
      dd = MFMA16(qa1, ka[nt][1], dd);
      unsigned lo = 0, hi = 0;
      #pragma unroll
      for (int jr = 0; jr < 4; ++jr) {
        const int qrow = kg * 4 + jr;
        const int u = nt * 16 + ln16 - qrow + 15;
        const float s = (dd[jr] + b2f(G[w][qrow][u])) * kScale + aqv[jr] + at4[nt];
        const float e = __expf(s) * linv[jr];
        const unsigned bb = f2b(e);
        if (jr == 0) lo = bb; else if (jr == 1) lo |= bb << 16;
        else if (jr == 2) hi = bb; else hi |= bb << 16;
      }
      *reinterpret_cast<uint2*>(&P[nt * 16 + ln16][w * 16 + kg * 4]) = make_uint2(lo, hi);
    }
    __syncthreads();                             // P complete
    const size_t vbase = (size_t)(w * 16 + ln16) * TT + qc * 64 + kg * 8;
    bf16x8 vf0 = ldb8(&vP[vbase]), vf1 = ldb8(&vP[vbase + 32]);
    #pragma unroll
    for (int nt = 0; nt < 4; ++nt) {
      bf16x8 pb0 = *reinterpret_cast<const bf16x8*>(&P[nt * 16 + ln16][kg * 8]);
      bf16x8 pb1 = *reinterpret_cast<const bf16x8*>(&P[nt * 16 + ln16][32 + kg * 8]);
      cacc[nt] = MFMA16(vf0, pb0, cacc[nt]);
      cacc[nt] = MFMA16(vf1, pb1, cacc[nt]);
    }
  }
  #pragma unroll
  for (int nt = 0; nt < 4; ++nt) {
    const int t = t0 + nt * 16 + ln16;
    ushort4 s4;
    s4.x = f2b(cacc[nt][0]); s4.y = f2b(cacc[nt][1]);
    s4.z = f2b(cacc[nt][2]); s4.w = f2b(cacc[nt][3]);
    *reinterpret_cast<ushort4*>(
      &ctx2[((size_t)b * TT + t) * 2048 + part * 512 + h * 64 + w * 16 + kg * 4]) = s4;
  }
}

// ---------- launch ----------
extern "C" void kernel_launch(void* const* d_in, const int* in_sizes, int n_in,
                              void* d_out, int out_size, void* d_ws, size_t ws_size,
                              hipStream_t stream)
{
  (void)in_sizes; (void)n_in; (void)out_size;
  const float* x     = (const float*)d_in[0];
  const float* pe    = (const float*)d_in[1];
  const float* xm    = (const float*)d_in[2];
  const float* gamma = (const float*)d_in[3];
  const float* beta  = (const float*)d_in[4];
  const float* Wq    = (const float*)d_in[5];
  const float* bq    = (const float*)d_in[6];
  const float* Wk    = (const float*)d_in[7];
  const float* bk    = (const float*)d_in[8];
  const float* Wv    = (const float*)d_in[9];
  const float* bv    = (const float*)d_in[10];
  const float* Wp    = (const float*)d_in[11];
  const float* ub    = (const float*)d_in[12];
  const float* vb    = (const float*)d_in[13];
  const float* Wo    = (const float*)d_in[14];
  const float* bo    = (const float*)d_in[15];

  // workspace layout (bytes)
  char* ws = (char*)d_ws;
  u16*  quB  = (u16*) (ws + 0);          // [32][1024][64] bf16  (4 MiB)
  u16*  kB   = (u16*) (ws + 4194304);    // [32][1024][64] bf16  (4 MiB)
  u16*  vB   = (u16*) (ws + 8388608);    // [32][64][1024] bf16  (4 MiB)
  u16*  pB   = (u16*) (ws + 12582912);   // [8][2048][64] bf16   (2 MiB)
  float* corrB = (float*)(ws + 14680064);// [8][2048] f32        (64 KiB)
  float* lsB = (float*)(ws + 14745600);  // [2][32][1024] f32    (256 KiB)
  u16*  Wo4  = (u16*) (ws + 15007744);   // [512][2048] bf16     (2 MiB)
  u16*  ctx2 = (u16*) (ws + 17104896);   // [4][1024][2048] bf16 (16 MiB)
  // dead-after-projections buffers overlaid INSIDE ctx2's region:
  u16*  xnT  = (u16*) (ws + 17104896);   // [4][1024][512] bf16  (4 MiB)
  u16*  posT = (u16*) (ws + 21299200);   // [2048][512] bf16     (2 MiB)
  u16*  Wstk = (u16*) (ws + 23396352);   // [2048][512] bf16     (2 MiB)
  if (ws_size < 33882112) return;

  dim3 blk(256);
  const long XS = (long)TT * CB;
  const long QS = (long)NH * TT * DH;

  convert_qkvp<<<dim3(512), blk, 0, stream>>>(Wq, Wk, Wv, Wp, Wstk);
  convert_wo4<<<dim3(128), blk, 0, stream>>>(Wo, Wo4);
  transpose_pe<<<dim3(32, 8), blk, 0, stream>>>(pe, posT);
  ln_kernel<<<dim3(32, 4), blk, 0, stream>>>(x, gamma, beta, xnT);

  proj_qkv<<<dim3(16, 48, 4), blk, 0, stream>>>(Wstk, xnT, bq, ub, bk, bv, quB, kB, vB);
  gemm_mfma<512, 1><<<dim3(32, 16, 1), blk, 0, stream>>>(
      Wstk + (size_t)1536 * 512, posT, 0, 0, 2048, nullptr, pB);
  corr_kernel<<<dim3(8, 8), blk, 0, stream>>>(pB, ub, vb, corrB);

  stats_mfma<<<dim3(2048), blk, 0, stream>>>(quB, kB, pB, corrB, xm, lsB);
  ctx_mfma<<<dim3(2048), blk, 0, stream>>>(quB, kB, vB, pB, corrB, xm, lsB, ctx2);

  gemm_mfma<2048, 0><<<dim3(16, 16, 4), blk, 0, stream>>>(
      Wo4, ctx2, (long)TT * 2048, (long)CB * TT, TT, bo, (float*)d_out);
}

// Round 6
// 207.813 us; speedup vs baseline: 1.5017x; 1.4980x over previous
//
#include <hip/hip_runtime.h>
#include <hip/hip_bf16.h>

typedef unsigned short u16;
typedef __bf16 bf16_t;
typedef bf16_t bf16x8 __attribute__((ext_vector_type(8)));
typedef float f32x4 __attribute__((ext_vector_type(4)));
typedef u16 u16x8 __attribute__((ext_vector_type(8)));

#define MFMA16(A,B,C) __builtin_amdgcn_mfma_f32_16x16x32_bf16(A,B,C,0,0,0)

#define CB 512
#define TT 1024
#define NH 8
#define DH 64
static __constant__ float kScale = 0.044194173824159216f; // 1/sqrt(512)

static __device__ __forceinline__ u16 f2b(float f) {
  unsigned u = __float_as_uint(f);
  unsigned r = u + 0x7FFFu + ((u >> 16) & 1u);
  return (u16)(r >> 16);
}
static __device__ __forceinline__ float b2f(u16 u) {
  return __uint_as_float(((unsigned)u) << 16);
}
static __device__ __forceinline__ bf16x8 ldb8(const u16* p) {
  return *reinterpret_cast<const bf16x8*>(p);
}

// ---------- Wq/Wk/Wv/Wp -> Wstk [2048][512] bf16 ; Wo -> WoB [512][512] bf16 ----------
__global__ __launch_bounds__(256)
void convert5(const float* __restrict__ Wq, const float* __restrict__ Wk,
              const float* __restrict__ Wv, const float* __restrict__ Wp,
              const float* __restrict__ Wo,
              u16* __restrict__ Wstk, u16* __restrict__ WoB)
{
  int i = blockIdx.x * 256 + threadIdx.x;      // 163840 groups of 8
  int sel = i >> 15, loc = i & 32767;
  const float* src = (sel == 0) ? Wq : (sel == 1) ? Wk : (sel == 2) ? Wv
                   : (sel == 3) ? Wp : Wo;
  const float4 a = ((const float4*)src)[loc * 2 + 0];
  const float4 b = ((const float4*)src)[loc * 2 + 1];
  u16x8 o;
  o[0] = f2b(a.x); o[1] = f2b(a.y); o[2] = f2b(a.z); o[3] = f2b(a.w);
  o[4] = f2b(b.x); o[5] = f2b(b.y); o[6] = f2b(b.z); o[7] = f2b(b.w);
  u16* dst = (sel < 4) ? (Wstk + (size_t)i * 8) : (WoB + (size_t)loc * 8);
  *(u16x8*)dst = o;
}

// ---------- pos_emb [512][2047] fp32 -> posT [2048][512] bf16 (row 2047 = 0) ----------
__global__ __launch_bounds__(256)
void transpose_pe(const float* __restrict__ pe, u16* __restrict__ posT)
{
  __shared__ float tile[64][65];
  int j0 = blockIdx.x * 64, c0 = blockIdx.y * 64;
  for (int e = threadIdx.x; e < 4096; e += 256) {
    int cc = e >> 6, jj = e & 63;
    int j = j0 + jj;
    tile[jj][cc] = (j < 2047) ? pe[(size_t)(c0 + cc) * 2047 + j] : 0.f;
  }
  __syncthreads();
  for (int e = threadIdx.x; e < 4096; e += 256) {
    int jj = e >> 6, cc = e & 63;
    posT[(size_t)(j0 + jj) * 512 + c0 + cc] = f2b(tile[jj][cc]);
  }
}

// ---------- LayerNorm over channel axis; emits xnT [b][t][c] bf16 ----------
__global__ __launch_bounds__(256)
void ln_kernel(const float* __restrict__ x, const float* __restrict__ gamma,
               const float* __restrict__ beta, u16* __restrict__ xnT)
{
  __shared__ float sred[8][33], ssred[8][33];
  int tl = threadIdx.x & 31, cg = threadIdx.x >> 5;
  int t = blockIdx.x * 32 + tl;
  int b = blockIdx.y;
  const float* xb = x + (size_t)b * CB * TT + t;
  float s = 0.f, ss = 0.f;
  for (int c = cg * 64; c < cg * 64 + 64; ++c) {
    float v = xb[(size_t)c * TT];
    s += v; ss += v * v;
  }
  sred[cg][tl] = s; ssred[cg][tl] = ss;
  __syncthreads();
  float S = 0.f, SS = 0.f;
  #pragma unroll
  for (int g = 0; g < 8; ++g) { S += sred[g][tl]; SS += ssred[g][tl]; }
  float mean = S * (1.f / 512.f);
  float var = SS * (1.f / 512.f) - mean * mean;
  float rstd = rsqrtf(var + 1e-5f);
  u16* orow = xnT + ((size_t)b * TT + t) * CB;
  for (int c8 = 0; c8 < 8; ++c8) {
    int c = cg * 64 + c8 * 8;
    u16x8 o;
    #pragma unroll
    for (int j = 0; j < 8; ++j) {
      float v = xb[(size_t)(c + j) * TT];
      o[j] = f2b((v - mean) * rstd * gamma[c + j] + beta[c + j]);
    }
    *(u16x8*)(orow + c) = o;
  }
}

// ---------- gemm2: wave 32m x 64n, block 64m x 128n ----------
// A bf16 [M][K], XT bf16 [N][K] (+ z*xStride). grid (N/128, M/64, Z).
// OMODE 0: f32 out[z*oStride + m*Nout + n]
// OMODE 1: u16 per-head transpose out[z*oStride + ((m>>6)*Nout + n)*64 + (m&63)]
template<int K, int OMODE>
__global__ __launch_bounds__(256)
void gemm2(const u16* __restrict__ A, const u16* __restrict__ XT,
           long xStride, long oStride, int Nout,
           const float* __restrict__ b0, void* __restrict__ outv)
{
  const int tid = threadIdx.x, w = tid >> 6, lane = tid & 63;
  const int ln16 = lane & 15, kg = lane >> 4;
  const int wm = w & 1, wn = w >> 1;
  const int m0 = blockIdx.y * 64 + wm * 32;
  const int n0 = blockIdx.x * 128 + wn * 64;
  const int z = blockIdx.z;
  const u16* Ar = A + (size_t)(m0 + ln16) * K + kg * 8;
  const u16* Br = XT + (size_t)z * xStride + (size_t)(n0 + ln16) * K + kg * 8;
  f32x4 acc[2][4] = {};
  #pragma unroll 2
  for (int ks = 0; ks < K / 32; ++ks) {
    bf16x8 a[2], bb[4];
    #pragma unroll
    for (int mt = 0; mt < 2; ++mt) a[mt] = ldb8(Ar + (size_t)mt * 16 * K + ks * 32);
    #pragma unroll
    for (int nt = 0; nt < 4; ++nt) bb[nt] = ldb8(Br + (size_t)nt * 16 * K + ks * 32);
    #pragma unroll
    for (int mt = 0; mt < 2; ++mt)
      #pragma unroll
      for (int nt = 0; nt < 4; ++nt)
        acc[mt][nt] = MFMA16(a[mt], bb[nt], acc[mt][nt]);
  }
  float add[2][4];
  #pragma unroll
  for (int mt = 0; mt < 2; ++mt)
    #pragma unroll
    for (int jr = 0; jr < 4; ++jr)
      add[mt][jr] = b0 ? b0[m0 + mt * 16 + kg * 4 + jr] : 0.f;
  #pragma unroll
  for (int mt = 0; mt < 2; ++mt)
    #pragma unroll
    for (int nt = 0; nt < 4; ++nt) {
      const int n = n0 + nt * 16 + ln16;
      if constexpr (OMODE == 0) {
        float* out = (float*)outv;
        #pragma unroll
        for (int jr = 0; jr < 4; ++jr)
          out[(size_t)z * oStride + (size_t)(m0 + mt * 16 + kg * 4 + jr) * Nout + n] =
              acc[mt][nt][jr] + add[mt][jr];
      } else {
        const int m_low = m0 + mt * 16;
        const size_t o = (size_t)z * oStride +
                         ((size_t)(m_low >> 6) * Nout + n) * 64 + (m_low & 63) + kg * 4;
        ushort4 s4;
        s4.x = f2b(acc[mt][nt][0] + add[mt][0]);
        s4.y = f2b(acc[mt][nt][1] + add[mt][1]);
        s4.z = f2b(acc[mt][nt][2] + add[mt][2]);
        s4.w = f2b(acc[mt][nt][3] + add[mt][3]);
        *reinterpret_cast<ushort4*>((u16*)outv + o) = s4;
      }
    }
}

// ---------- fused q/k/v projection with gemm2 tile ----------
// grid (8, 24, 4): my -> sec = my>>3 (0=q,1=k,2=v), m0l = (my&7)*64 + wm*32.
__global__ __launch_bounds__(256)
void proj_qkv2(const u16* __restrict__ Wstk, const u16* __restrict__ xnT,
               const float* __restrict__ bq, const float* __restrict__ ub,
               const float* __restrict__ bk, const float* __restrict__ bv,
               u16* __restrict__ quB, u16* __restrict__ kB, u16* __restrict__ vB)
{
  const int tid = threadIdx.x, w = tid >> 6, lane = tid & 63;
  const int ln16 = lane & 15, kg = lane >> 4;
  const int wm = w & 1, wn = w >> 1;
  const int my = blockIdx.y;
  const int sec = my >> 3;
  const int m0l = (my & 7) * 64 + wm * 32;
  const int n0 = blockIdx.x * 128 + wn * 64;
  const int z = blockIdx.z;
  const long XS = (long)TT * CB;
  const long QS = (long)NH * TT * DH;
  const u16* Ar = Wstk + (size_t)(sec * 512 + m0l + ln16) * 512 + kg * 8;
  const u16* Br = xnT + (size_t)z * XS + (size_t)(n0 + ln16) * 512 + kg * 8;
  f32x4 acc[2][4] = {};
  #pragma unroll 2
  for (int ks = 0; ks < 16; ++ks) {
    bf16x8 a[2], bb[4];
    #pragma unroll
    for (int mt = 0; mt < 2; ++mt) a[mt] = ldb8(Ar + (size_t)mt * 16 * 512 + ks * 32);
    #pragma unroll
    for (int nt = 0; nt < 4; ++nt) bb[nt] = ldb8(Br + (size_t)nt * 16 * 512 + ks * 32);
    #pragma unroll
    for (int mt = 0; mt < 2; ++mt)
      #pragma unroll
      for (int nt = 0; nt < 4; ++nt)
        acc[mt][nt] = MFMA16(a[mt], bb[nt], acc[mt][nt]);
  }
  float add[2][4];
  #pragma unroll
  for (int mt = 0; mt < 2; ++mt)
    #pragma unroll
    for (int jr = 0; jr < 4; ++jr) {
      int m = m0l + mt * 16 + kg * 4 + jr;
      add[mt][jr] = (sec == 0) ? (bq[m] + ub[m]) : (sec == 1) ? bk[m] : bv[m];
    }
  if (sec < 2) {
    u16* dst = sec ? kB : quB;
    #pragma unroll
    for (int mt = 0; mt < 2; ++mt)
      #pragma unroll
      for (int nt = 0; nt < 4; ++nt) {
        const int n = n0 + nt * 16 + ln16;
        const int m_low = m0l + mt * 16;
        const size_t o = (size_t)z * QS +
                         ((size_t)(m_low >> 6) * TT + n) * 64 + (m_low & 63) + kg * 4;
        ushort4 s4;
        s4.x = f2b(acc[mt][nt][0] + add[mt][0]);
        s4.y = f2b(acc[mt][nt][1] + add[mt][1]);
        s4.z = f2b(acc[mt][nt][2] + add[mt][2]);
        s4.w = f2b(acc[mt][nt][3] + add[mt][3]);
        *reinterpret_cast<ushort4*>(dst + o) = s4;
      }
  } else {
    #pragma unroll
    for (int mt = 0; mt < 2; ++mt)
      #pragma unroll
      for (int nt = 0; nt < 4; ++nt) {
        const int n = n0 + nt * 16 + ln16;
        #pragma unroll
        for (int jr = 0; jr < 4; ++jr)
          vB[(size_t)z * QS + (size_t)(m0l + mt * 16 + kg * 4 + jr) * TT + n] =
              f2b(acc[mt][nt][jr] + add[mt][jr]);
      }
  }
}

// ---------- corr[h][j] = sum_d (vb-ub)[h][d] * p[h][j][d] ----------
__global__ __launch_bounds__(256)
void corr_kernel(const u16* __restrict__ pp, const float* __restrict__ ub,
                 const float* __restrict__ vb, float* __restrict__ corr)
{
  const int h = blockIdx.y;
  const int j = blockIdx.x * 256 + threadIdx.x;
  __shared__ float dl[64];
  if (threadIdx.x < 64)
    dl[threadIdx.x] = vb[h * 64 + threadIdx.x] - ub[h * 64 + threadIdx.x];
  __syncthreads();
  const u16* prow = pp + ((size_t)h * 2048 + j) * 64;
  float s = 0.f;
  #pragma unroll
  for (int d8 = 0; d8 < 8; ++d8) {
    union { bf16x8 v; u16 u[8]; } pu;
    pu.v = ldb8(prow + d8 * 8);
    #pragma unroll
    for (int e = 0; e < 8; ++e) s += b2f(pu.u[e]) * dl[d8 * 8 + e];
  }
  corr[h * 2048 + j] = s;
}

// ---------- Pass 1 (MFMA): partial l over a ki half ----------
__global__ __launch_bounds__(256)
void stats_mfma(const u16* __restrict__ qu, const u16* __restrict__ kk_,
                const u16* __restrict__ pp, const float* __restrict__ corr,
                const float* __restrict__ xmask, float* __restrict__ ls)
{
  const int tid = threadIdx.x;
  const int w = tid >> 6, lane = tid & 63;
  const int ln16 = lane & 15, kg = lane >> 4;
  const int bid = blockIdx.x;
  const int bh = (bid & 7) + 8 * ((bid >> 3) & 3);
  const int rest = bid >> 5;
  const int qi0 = (rest & 31) * 32;
  const int part = rest >> 5;
  const int b = bh >> 3, h = bh & 7;
  const u16* quP = qu + (size_t)bh * TT * DH;
  const u16* kP  = kk_ + (size_t)bh * TT * DH;
  const u16* pP  = pp + (size_t)h * 2048 * DH;
  const float* corrP = corr + (h << 11);

  __shared__ u16 G[4][32][100];
  __shared__ float red[4][32];

  bf16x8 qa[2][2];
  #pragma unroll
  for (int mt = 0; mt < 2; ++mt)
    #pragma unroll
    for (int kc = 0; kc < 2; ++kc)
      qa[mt][kc] = ldb8(&quP[(size_t)(qi0 + mt * 16 + ln16) * DH + kc * 32 + kg * 8]);
  float aq[2][4];
  #pragma unroll
  for (int mt = 0; mt < 2; ++mt)
    #pragma unroll
    for (int jr = 0; jr < 4; ++jr)
      aq[mt][jr] = (xmask[b * TT + qi0 + mt * 16 + kg * 4 + jr] - 1.f) * 10000.f;

  float rs[2][4] = {};
  for (int c = 0; c < 2; ++c) {
    const int ki0 = (part * 8 + c * 4 + w) * 64;
    const int j0 = ki0 - qi0 + 992;
    #pragma unroll
    for (int nt = 0; nt < 6; ++nt) {
      const size_t po = (size_t)(j0 + nt * 16 + ln16) * DH + kg * 8;
      bf16x8 pb0 = ldb8(&pP[po]);
      bf16x8 pb1 = ldb8(&pP[po + 32]);
      const float cval = corrP[j0 + nt * 16 + ln16];
      #pragma unroll
      for (int mt = 0; mt < 2; ++mt) {
        f32x4 g = {0.f, 0.f, 0.f, 0.f};
        g = MFMA16(qa[mt][0], pb0, g);
        g = MFMA16(qa[mt][1], pb1, g);
        #pragma unroll
        for (int jr = 0; jr < 4; ++jr)
          G[w][mt * 16 + kg * 4 + jr][nt * 16 + ln16] = f2b(g[jr] + cval);
      }
    }
    #pragma unroll
    for (int nt = 0; nt < 4; ++nt) {
      const size_t ko = (size_t)(ki0 + nt * 16 + ln16) * DH + kg * 8;
      bf16x8 kb0 = ldb8(&kP[ko]);
      bf16x8 kb1 = ldb8(&kP[ko + 32]);
      const float ak = (xmask[b * TT + ki0 + nt * 16 + ln16] - 1.f) * 10000.f;
      #pragma unroll
      for (int mt = 0; mt < 2; ++mt) {
        f32x4 dd = {0.f, 0.f, 0.f, 0.f};
        dd = MFMA16(qa[mt][0], kb0, dd);
        dd = MFMA16(qa[mt][1], kb1, dd);
        #pragma unroll
        for (int jr = 0; jr < 4; ++jr) {
          const int qrow = mt * 16 + kg * 4 + jr;
          const int u = nt * 16 + ln16 - qrow + 31;
          const float s = (dd[jr] + b2f(G[w][qrow][u])) * kScale + aq[mt][jr] + ak;
          rs[mt][jr] += __expf(s);
        }
      }
    }
  }
  #pragma unroll
  for (int mt = 0; mt < 2; ++mt)
    #pragma unroll
    for (int jr = 0; jr < 4; ++jr) {
      float v = rs[mt][jr];
      v += __shfl_xor(v, 1); v += __shfl_xor(v, 2);
      v += __shfl_xor(v, 4); v += __shfl_xor(v, 8);
      rs[mt][jr] = v;
    }
  if (ln16 == 0) {
    #pragma unroll
    for (int mt = 0; mt < 2; ++mt)
      #pragma unroll
      for (int jr = 0; jr < 4; ++jr)
        red[w][mt * 16 + kg * 4 + jr] = rs[mt][jr];
  }
  __syncthreads();
  if (tid < 32)
    ls[(size_t)part * 32768 + (size_t)bh * TT + qi0 + tid] =
        red[0][tid] + red[1][tid] + red[2][tid] + red[3][tid];
}

// ---------- Pass 2 (MFMA): partial ctx; t-tile 64, qi split 4-way ----------
__global__ __launch_bounds__(256)
void ctx_mfma(const u16* __restrict__ qu, const u16* __restrict__ kk_,
              const u16* __restrict__ vv, const u16* __restrict__ pp,
              const float* __restrict__ corr, const float* __restrict__ xmask,
              const float* __restrict__ ls, u16* __restrict__ ctx2)
{
  const int tid = threadIdx.x;
  const int w = tid >> 6, lane = tid & 63;
  const int ln16 = lane & 15, kg = lane >> 4;
  const int bid = blockIdx.x;
  const int bh = (bid & 7) + 8 * ((bid >> 3) & 3);
  const int rest = bid >> 5;
  const int t0 = (rest & 15) * 64;
  const int part = rest >> 4;
  const int b = bh >> 3, h = bh & 7;
  const u16* quP = qu + (size_t)bh * TT * DH;
  const u16* kP  = kk_ + (size_t)bh * TT * DH;
  const u16* vP  = vv + (size_t)bh * DH * TT;
  const u16* pP  = pp + (size_t)h * 2048 * DH;
  const float* corrP = corr + (h << 11);
  const float* lsP = ls + (size_t)bh * TT;

  __shared__ u16 G[4][16][84];
  __shared__ __align__(16) u16 P[64][80];

  bf16x8 ka[4][2];
  #pragma unroll
  for (int nt = 0; nt < 4; ++nt)
    #pragma unroll
    for (int kc = 0; kc < 2; ++kc)
      ka[nt][kc] = ldb8(&kP[(size_t)(t0 + nt * 16 + ln16) * DH + kc * 32 + kg * 8]);
  float at4[4];
  #pragma unroll
  for (int nt = 0; nt < 4; ++nt)
    at4[nt] = (xmask[b * TT + t0 + nt * 16 + ln16] - 1.f) * 10000.f;

  f32x4 cacc[4] = {};
  for (int qc = part * 4; qc < part * 4 + 4; ++qc) {
    const int qw = qc * 64 + w * 16;
    const int j0 = t0 - qw + 1008;
    const size_t qo = (size_t)(qw + ln16) * DH + kg * 8;
    bf16x8 qa0 = ldb8(&quP[qo]), qa1 = ldb8(&quP[qo + 32]);
    #pragma unroll
    for (int nt = 0; nt < 5; ++nt) {
      const size_t po = (size_t)(j0 + nt * 16 + ln16) * DH + kg * 8;
      bf16x8 pb0 = ldb8(&pP[po]), pb1 = ldb8(&pP[po + 32]);
      const float cval = corrP[j0 + nt * 16 + ln16];
      f32x4 g = {0.f, 0.f, 0.f, 0.f};
      g = MFMA16(qa0, pb0, g);
      g = MFMA16(qa1, pb1, g);
      #pragma unroll
      for (int jr = 0; jr < 4; ++jr)
        G[w][kg * 4 + jr][nt * 16 + ln16] = f2b(g[jr] + cval);
    }
    float linv[4], aqv[4];
    #pragma unroll
    for (int jr = 0; jr < 4; ++jr) {
      const int qi = qw + kg * 4 + jr;
      linv[jr] = 1.f / (lsP[qi] + lsP[32768 + qi]);
      aqv[jr] = (xmask[b * TT + qi] - 1.f) * 10000.f;
    }
    __syncthreads();
    #pragma unroll
    for (int nt = 0; nt < 4; ++nt) {
      f32x4 dd = {0.f, 0.f, 0.f, 0.f};
      dd = MFMA16(qa0, ka[nt][0], dd);
      dd = MFMA16(qa1, ka[nt][1], dd);
      unsigned lo = 0, hi = 0;
      #pragma unroll
      for (int jr = 0; jr < 4; ++jr) {
        const int qrow = kg * 4 + jr;
        const int u = nt * 16 + ln16 - qrow + 15;
        const float s = (dd[jr] + b2f(G[w][qrow][u])) * kScale + aqv[jr] + at4[nt];
        const float e = __expf(s) * linv[jr];
        const unsigned bb = f2b(e);
        if (jr == 0) lo = bb; else if (jr == 1) lo |= bb << 16;
        else if (jr == 2) hi = bb; else hi |= bb << 16;
      }
      *reinterpret_cast<uint2*>(&P[nt * 16 + ln16][w * 16 + kg * 4]) = make_uint2(lo, hi);
    }
    __syncthreads();
    const size_t vbase = (size_t)(w * 16 + ln16) * TT + qc * 64 + kg * 8;
    bf16x8 vf0 = ldb8(&vP[vbase]), vf1 = ldb8(&vP[vbase + 32]);
    #pragma unroll
    for (int nt = 0; nt < 4; ++nt) {
      bf16x8 pb0 = *reinterpret_cast<const bf16x8*>(&P[nt * 16 + ln16][kg * 8]);
      bf16x8 pb1 = *reinterpret_cast<const bf16x8*>(&P[nt * 16 + ln16][32 + kg * 8]);
      cacc[nt] = MFMA16(vf0, pb0, cacc[nt]);
      cacc[nt] = MFMA16(vf1, pb1, cacc[nt]);
    }
  }
  #pragma unroll
  for (int nt = 0; nt < 4; ++nt) {
    const int t = t0 + nt * 16 + ln16;
    ushort4 s4;
    s4.x = f2b(cacc[nt][0]); s4.y = f2b(cacc[nt][1]);
    s4.z = f2b(cacc[nt][2]); s4.w = f2b(cacc[nt][3]);
    *reinterpret_cast<ushort4*>(
      &ctx2[((size_t)b * TT + t) * 2048 + part * 512 + h * 64 + w * 16 + kg * 4]) = s4;
  }
}

// ---------- sum 4 ctx partials -> ctxS [b][t][512] bf16 ----------
__global__ __launch_bounds__(256)
void reduce_ctx(const u16* __restrict__ ctx2, u16* __restrict__ ctxS)
{
  int i = blockIdx.x * 256 + threadIdx.x;      // 262144 groups of 8
  int row = i >> 6;
  int c0 = (i & 63) * 8;
  const u16* src = ctx2 + (size_t)row * 2048 + c0;
  float s[8] = {};
  #pragma unroll
  for (int p = 0; p < 4; ++p) {
    union { u16x8 v; u16 u[8]; } t;
    t.v = *(const u16x8*)(src + p * 512);
    #pragma unroll
    for (int e = 0; e < 8; ++e) s[e] += b2f(t.u[e]);
  }
  u16x8 o;
  #pragma unroll
  for (int e = 0; e < 8; ++e) o[e] = f2b(s[e]);
  *(u16x8*)(ctxS + (size_t)row * 512 + c0) = o;
}

// ---------- launch ----------
extern "C" void kernel_launch(void* const* d_in, const int* in_sizes, int n_in,
                              void* d_out, int out_size, void* d_ws, size_t ws_size,
                              hipStream_t stream)
{
  (void)in_sizes; (void)n_in; (void)out_size;
  const float* x     = (const float*)d_in[0];
  const float* pe    = (const float*)d_in[1];
  const float* xm    = (const float*)d_in[2];
  const float* gamma = (const float*)d_in[3];
  const float* beta  = (const float*)d_in[4];
  const float* Wq    = (const float*)d_in[5];
  const float* bq    = (const float*)d_in[6];
  const float* Wk    = (const float*)d_in[7];
  const float* bk    = (const float*)d_in[8];
  const float* Wv    = (const float*)d_in[9];
  const float* bv    = (const float*)d_in[10];
  const float* Wp    = (const float*)d_in[11];
  const float* ub    = (const float*)d_in[12];
  const float* vb    = (const float*)d_in[13];
  const float* Wo    = (const float*)d_in[14];
  const float* bo    = (const float*)d_in[15];

  // workspace layout (bytes), total 32,309,248 <= 33,882,112 known-safe
  char* ws = (char*)d_ws;
  u16*  quB  = (u16*) (ws + 0);          // [32][1024][64] bf16  (4 MiB)
  u16*  ctxS = (u16*) (ws + 0);          // [4][1024][512] bf16  (overlay: quB dead)
  u16*  kB   = (u16*) (ws + 4194304);    // [32][1024][64] bf16  (4 MiB)
  u16*  vB   = (u16*) (ws + 8388608);    // [32][64][1024] bf16  (4 MiB)
  u16*  pB   = (u16*) (ws + 12582912);   // [8][2048][64] bf16   (2 MiB)
  float* corrB = (float*)(ws + 14680064);// [8][2048] f32        (64 KiB)
  float* lsB = (float*)(ws + 14745600);  // [2][32][1024] f32    (256 KiB)
  u16*  WoB  = (u16*) (ws + 15007744);   // [512][512] bf16      (512 KiB)
  u16*  ctx2 = (u16*) (ws + 15532032);   // [4][1024][2048] bf16 (16 MiB)
  // staging (dead before ctx2 is written) overlaid inside ctx2's region:
  u16*  xnT  = (u16*) (ws + 15532032);   // [4][1024][512] bf16  (4 MiB)
  u16*  posT = (u16*) (ws + 19726336);   // [2048][512] bf16     (2 MiB)
  u16*  Wstk = (u16*) (ws + 21823488);   // [2048][512] bf16     (2 MiB)
  if (ws_size < 32309248) return;

  dim3 blk(256);

  convert5<<<dim3(640), blk, 0, stream>>>(Wq, Wk, Wv, Wp, Wo, Wstk, WoB);
  transpose_pe<<<dim3(32, 8), blk, 0, stream>>>(pe, posT);
  ln_kernel<<<dim3(32, 4), blk, 0, stream>>>(x, gamma, beta, xnT);

  proj_qkv2<<<dim3(8, 24, 4), blk, 0, stream>>>(Wstk, xnT, bq, ub, bk, bv, quB, kB, vB);
  gemm2<512, 1><<<dim3(16, 8, 1), blk, 0, stream>>>(
      Wstk + (size_t)1536 * 512, posT, 0, 0, 2048, nullptr, pB);
  corr_kernel<<<dim3(8, 8), blk, 0, stream>>>(pB, ub, vb, corrB);

  stats_mfma<<<dim3(2048), blk, 0, stream>>>(quB, kB, pB, corrB, xm, lsB);
  ctx_mfma<<<dim3(2048), blk, 0, stream>>>(quB, kB, vB, pB, corrB, xm, lsB, ctx2);
  reduce_ctx<<<dim3(1024), blk, 0, stream>>>(ctx2, ctxS);

  gemm2<512, 0><<<dim3(8, 8, 4), blk, 0, stream>>>(
      WoB, ctxS, (long)TT * CB, (long)CB * TT, TT, bo, (float*)d_out);
}